// Round 1
// baseline (197.828 us; speedup 1.0000x reference)
//
#include <hip/hip_runtime.h>
#include <hip/hip_bf16.h>

// ParamTable: idx = base-2 encoding of x_pa row (MSB first), p = params[idx],
// outputs (p[:,0], p[:,1]) concatenated flat -> out[0..B) , out[B..2B).
//
// Memory-bound: 128 MiB x_pa read + 16 MiB write + ~512 KiB table (L2-resident).

__global__ __launch_bounds__(256) void paramtable_gather_kernel(
    const int* __restrict__ x_pa,      // [B,16] values in {0,1}
    const float* __restrict__ params,  // [65536, 2]
    float* __restrict__ out,           // [2*B]: first col then second col
    int B) {
    int b = blockIdx.x * blockDim.x + threadIdx.x;
    if (b >= B) return;

    const int4* row = reinterpret_cast<const int4*>(x_pa) + (size_t)b * 4;
    int4 a0 = row[0];
    int4 a1 = row[1];
    int4 a2 = row[2];
    int4 a3 = row[3];

    unsigned idx =
        ((unsigned)a0.x << 15) | ((unsigned)a0.y << 14) |
        ((unsigned)a0.z << 13) | ((unsigned)a0.w << 12) |
        ((unsigned)a1.x << 11) | ((unsigned)a1.y << 10) |
        ((unsigned)a1.z << 9)  | ((unsigned)a1.w << 8)  |
        ((unsigned)a2.x << 7)  | ((unsigned)a2.y << 6)  |
        ((unsigned)a2.z << 5)  | ((unsigned)a2.w << 4)  |
        ((unsigned)a3.x << 3)  | ((unsigned)a3.y << 2)  |
        ((unsigned)a3.z << 1)  |  (unsigned)a3.w;

    float2 p = reinterpret_cast<const float2*>(params)[idx];
    out[b]     = p.x;
    out[B + b] = p.y;
}

extern "C" void kernel_launch(void* const* d_in, const int* in_sizes, int n_in,
                              void* d_out, int out_size, void* d_ws, size_t ws_size,
                              hipStream_t stream) {
    // setup_inputs order: x [B] (unused), x_pa [B*16], params [65536*2]
    const int*   x_pa   = (const int*)d_in[1];
    const float* params = (const float*)d_in[2];
    float*       out    = (float*)d_out;

    int B = in_sizes[0];  // x has B elements

    int threads = 256;
    int blocks  = (B + threads - 1) / threads;
    paramtable_gather_kernel<<<blocks, threads, 0, stream>>>(x_pa, params, out, B);
}